// Round 2
// baseline (1774.465 us; speedup 1.0000x reference)
//
#include <hip/hip_runtime.h>

#define BT   (512*256)
// hbuf (bytes): zeros @0..127, pad, h @192..319  (==64 mod 128: h line banks
// 16-31 for a0 / 0-15 for a1, opposite zero-lane banks -> max 2-way, free)
#define HB0b 192
#define HLENb 320
#define LOG2E 1.44269504088896f

using short8  = __attribute__((ext_vector_type(8))) short;
using floatx4 = __attribute__((ext_vector_type(4))) float;
using int4v   = __attribute__((ext_vector_type(4))) int;
using ushort4v= __attribute__((ext_vector_type(4))) unsigned short;

__device__ inline unsigned short f2bf(float f){
  unsigned int u = __float_as_uint(f);
  u += 0x7FFFu + ((u >> 16) & 1u);          // RNE
  return (unsigned short)(u >> 16);
}
__device__ inline float bf2f(unsigned short u){
  return __uint_as_float(((unsigned int)u) << 16);
}
__device__ inline float rcpf(float x){ return __builtin_amdgcn_rcpf(x); }
__device__ inline float ex2(float x){ return __builtin_amdgcn_exp2f(x); }

// 512 blocks x 512 threads, ONE batch per block -> 2 blocks/CU (4 waves/SIMD
// from two INDEPENDENTLY-barriered workgroups). The LSTM recurrence is pure
// latency (serial ds_read->MFMA->nonlin->barrier chain); anti-phase blocks
// fill each other's stalls. launch_bounds(512,2) caps VGPR at 128 (have 92)
// to guarantee co-residency. Gate matmul in INT8 MFMA (mfma_i32_16x16x64_i8),
// h quantized i8 scale 127, W per-row scale. A rows {0,4,8,12} all carry this
// block's batch (dup x4) -> every quad gets the gates in acc[g][0] natively.
// x-gates: bf16 MFMA in phase A -> f32 registers via 32 ds_bpermute.
// log2e folded into dq/bsum/W_ih so sigmoid exps are bare v_exp (exp2).
__global__ __launch_bounds__(512,2) void k_seq(
    const float* __restrict__ in,
    const float* __restrict__ Wih,  const float* __restrict__ Whh,
    const float* __restrict__ bih,  const float* __restrict__ bhh,
    const float* __restrict__ fc1w, const float* __restrict__ fc1b,
    const float* __restrict__ fc2w, const float* __restrict__ fc2b,
    const float* __restrict__ i1w,  const float* __restrict__ i1b,
    const float* __restrict__ i3w,  const float* __restrict__ i3b,
    const float* __restrict__ scw,  const float* __restrict__ zonew,
    float* __restrict__ out)
{
  __shared__ __align__(16) signed char hbuf[2][HLENb];     // i8 h + zero region
  __shared__ __align__(16) float scratch[640];             // int-module weights
  __shared__ __align__(8)  unsigned short toutl[256];      // bf16 TOut history
  __shared__ __align__(8)  unsigned short extl[256];       // bf16 Ext results
  __shared__ __align__(16) unsigned short exl[1024];       // bf16 Ext_X cols [t][4]
  __shared__ float t0l[256];                               // T0 f32
  __shared__ float hvitl[256];                             // HVAC + int_all f32
  __shared__ __align__(16) float parts[8];                 // fc2 wave partials

  const int tid = threadIdx.x;
  const int wv  = tid >> 6;             // 0..7
  const int ln  = tid & 63;
  const int l15 = ln & 15;
  const int quad= ln >> 4;
  const int bb  = blockIdx.x;           // == batch index

  // ---- init: stage per-block tables ----
  if(tid<256){
    const float* row = in + bb*1792 + tid*7;
    t0l[tid] = row[0];
    exl[tid*4+0]=f2bf(row[1]); exl[tid*4+1]=f2bf(row[2]);
    exl[tid*4+2]=f2bf(row[3]); exl[tid*4+3]=f2bf(row[4]);
  }
  for(int p=tid; p<2*HLENb; p+=512) ((signed char*)hbuf)[p]=0;
  if(tid<8) toutl[tid] = f2bf(in[bb*1792+tid*7]);
  float* lw4 = scratch;
  float* l3  = scratch + 512;
  if(tid>=256 && tid<384){
    int j=tid-256;
    lw4[j*4+0]=i1w[j*3+0]; lw4[j*4+1]=i1w[j*3+1];
    lw4[j*4+2]=i1w[j*3+2]; lw4[j*4+3]=i1b[j];
    l3[j]=i3w[j];
  }
  __syncthreads();
  if(tid<128) hbuf[0][HB0b+tid] = 127;   // h=1.0 -> q=127

  // ---- fused int module (one t per thread, tid<256) ----
  if(tid<256){
    const float b30=i3b[0], sc0=scw[0];
    int t=tid;
    const float* row = in + bb*1792 + t*7;
    float x0=row[3],x1=row[4],x2=row[5], acc=0.f;
    #pragma unroll 8
    for(int j=0;j<128;j++){
      float r=fmaxf(lw4[j*4]*x0+lw4[j*4+1]*x1+lw4[j*4+2]*x2+lw4[j*4+3],0.f);
      acc += r*l3[j];
    }
    float v = rcpf(1.f+__expf(-(acc+b30)))*sc0;
    float itv = (t<8)?0.f:v;
    hvitl[t] = row[6] + itv;
    out[3*BT+bb*256+t]=itv;              // Int_list
    out[BT+bb*256+t]=row[6];             // HVAC_list
    if(t<8){ out[bb*256+t]=row[0]; out[2*BT+bb*256+t]=0.f; }
  }

  // ---- i8 weight quantization (per-row scale) into VGPRs ----
  int4v wq[4][2];        // [gate][K-chunk], rows n = 128g + 16wv + l15
  float dq[4];
  short8 xfr[4];         // W_ih bf16 (pre-scaled by log2e), K=32 pad (5 valid)
  float  bsum[4];
  #pragma unroll
  for(int g=0;g<4;g++){
    int n = 128*g + 16*wv + l15;
    bsum[g] = (bih[n]+bhh[n])*LOG2E;
    const float* wr = Whh + n*128;
    float mx = 1e-20f;
    for(int j=0;j<128;j++) mx = fmaxf(mx, fabsf(wr[j]));
    float qs = 127.f/mx;
    dq[g] = mx * (LOG2E/16129.f);        // log2e/127^2
    #pragma unroll
    for(int c=0;c<2;c++){
      int4v v4;
      #pragma unroll
      for(int d=0;d<4;d++){
        int pk=0;
        #pragma unroll
        for(int bq=0;bq<4;bq++){
          int kk = c*64 + quad*16 + d*4 + bq;
          int q = __float2int_rn(wr[kk]*qs);
          pk |= (q & 255) << (8*bq);
        }
        v4[d]=pk;
      }
      wq[g][c]=v4;
    }
    short8 f;
    #pragma unroll
    for(int j=0;j<8;j++){ int kk=quad*8+j; f[j]=(short)f2bf(kk<5?Wih[n*5+kk]*LOG2E:0.f); }
    xfr[g]=f;
  }
  int4v fq[2]; float dqf;                // fc1 i8 (NOT log2e-scaled), row n2 = 16wv + l15
  {
    int n2 = 16*wv + l15;
    const float* fr = fc1w + n2*128;
    float mx = 1e-20f;
    for(int j=0;j<128;j++) mx = fmaxf(mx, fabsf(fr[j]));
    float qs = 127.f/mx;
    dqf = mx * (1.f/16129.f);
    #pragma unroll
    for(int c=0;c<2;c++){
      int4v v4;
      #pragma unroll
      for(int d=0;d<4;d++){
        int pk=0;
        #pragma unroll
        for(int bq=0;bq<4;bq++){
          int kk = c*64 + quad*16 + d*4 + bq;
          int q = __float2int_rn(fr[kk]*qs);
          pk |= (q & 255) << (8*bq);
        }
        v4[d]=pk;
      }
      fq[c]=v4;
    }
  }

  // ---- per-lane persistent scalars ----
  const int  u     = 16*wv + l15;           // this lane's unit
  const int  arow  = ((l15&3)==0) ? HB0b : 0;   // rows 0,4,8,12 = batch; else zero
  const int  aoff  = arow + quad*16;
  const int  hwoff = HB0b + u;
  const int  bpa0  = l15<<2;                // bpermute byte addr, k<4 (rows 0-3)
  const int  bpa1  = bpa0 + 64;             // k>=4 (rows 4-7, lanes 16-31)
  const float fb    = fc1b[u];
  const float fcw_u = fc2w[u];
  const float fc2b0 = fc2b[0];
  const float zwv   = zonew[0];
  const floatx4 ZV  = {0.f,0.f,0.f,0.f};
  const int4v   ZI  = {0,0,0,0};
  const short8  Z8  = 0;
  float E0 = in[bb*1792 + 56];              // E in EVERY lane's registers
  float c0 = 1.f;
  __syncthreads();

  #pragma unroll 1
  for(int i=8;i<256;i++){
    // ===== phase A: deferred E-update (i-1), TOut, embed, x-MFMA+bpermute =====
    if(i>8){
      floatx4 pa=*(const floatx4*)&parts[0];
      floatx4 pb=*(const floatx4*)&parts[4];
      float ext0=((pa[0]+pa[1])+(pa[2]+pa[3]))+((pb[0]+pb[1])+(pb[2]+pb[3]))+fc2b0;
      int ip = i-1;
      float tot0 = ext0 + hvitl[ip];
      if(ip<128){
        float ratio=(float)ip*0.0078125f;
        E0 = ratio*t0l[ip] + (1.f-ratio)*E0 + tot0*zwv;
      } else {
        E0 += tot0*zwv;
      }
      if(tid==0) extl[ip]=f2bf(ext0);
    }
    if(tid==0) toutl[i]=f2bf(E0);            // TOut[:,i]=E
    float xv[8][4];                          // x-gates, f32, register-resident
    {
      short8 ea = Z8;
      if(ln<8){                              // rows 0-7 = window slots
        int p=i-7+ln;
        float tos = (p==i) ? E0 : bf2f(toutl[p]);
        float tmix;
        if(i<128){
          float ratio=(float)i*0.0078125f;
          tmix = t0l[p]*ratio + tos*(1.f-ratio);
        } else tmix = tos;
        ea[0]=(short)f2bf(tmix);
        ushort4v e4 = *(const ushort4v*)&exl[p*4];
        ea[1]=(short)e4[0]; ea[2]=(short)e4[1];
        ea[3]=(short)e4[2]; ea[4]=(short)e4[3];
      }
      #pragma unroll
      for(int g=0;g<4;g++){
        floatx4 z=__builtin_amdgcn_mfma_f32_16x16x32_bf16(ea, xfr[g], ZV,0,0,0);
        #pragma unroll
        for(int r=0;r<4;r++){
          int zi = __float_as_int(z[r]+bsum[g]);
          xv[r][g]   = __int_as_float(__builtin_amdgcn_ds_bpermute(bpa0, zi));
          xv[r+4][g] = __int_as_float(__builtin_amdgcn_ds_bpermute(bpa1, zi));
        }
      }
    }
    // NO barrier here: hbuf/parts already fenced by prev iter's barriers.

    // ===== 8 inner LSTM steps: 8 i8 MFMAs/wave, single nonlin chain =====
    #pragma unroll
    for(int k=0;k<8;k++){
      const signed char* hb = &hbuf[k&1][0];
      int4v a0 = *(const int4v*)(hb + aoff);        // K 0..63
      int4v a1 = *(const int4v*)(hb + aoff + 64);   // K 64..127
      int4v acc[4];
      #pragma unroll
      for(int g=0;g<4;g++){
        int4v z = __builtin_amdgcn_mfma_i32_16x16x64_i8(a0, wq[g][0], ZI,0,0,0);
        z = __builtin_amdgcn_mfma_i32_16x16x64_i8(a1, wq[g][1], z,0,0,0);
        acc[g]=z;
      }
      float gi=fmaf((float)acc[0][0],dq[0],xv[k][0]);   // all in log2e domain
      float gf=fmaf((float)acc[1][0],dq[1],xv[k][1]);
      float gg=fmaf((float)acc[2][0],dq[2],xv[k][2]);
      float go=fmaf((float)acc[3][0],dq[3],xv[k][3]);
      float ef =ex2(-gf);                               // bare v_exp
      float egi=ex2(-gi);
      float egg=ex2(-2.f*gg);
      float sf = rcpf(1.f+ef);
      float itn=(1.f-egg)*rcpf((1.f+egi)*(1.f+egg));
      c0 = sf*c0 + itn;
      float ego=ex2(-go);
      float ec =ex2(-2.8853900818f*c0);                 // c unscaled: x2log2e
      float hv2=(1.f-ec)*rcpf((1.f+ego)*(1.f+ec));
      int q = __float2int_rn(hv2*127.f);                // |h|<1 -> |q|<=127
      hbuf[(k+1)&1][hwoff] = (signed char)q;            // quads 1-3 dup same value
      __syncthreads();
    }

    // ===== fc1 (i8) + within-quad fc2 reduce =====
    {
      const signed char* hb = &hbuf[0][0];
      int4v a0 = *(const int4v*)(hb + aoff);
      int4v a1 = *(const int4v*)(hb + aoff + 64);
      int4v z = __builtin_amdgcn_mfma_i32_16x16x64_i8(a0, fq[0], ZI,0,0,0);
      z = __builtin_amdgcn_mfma_i32_16x16x64_i8(a1, fq[1], z,0,0,0);
      float fv = (float)z[0]*dqf + fb;
      float pv = fmaxf(fv,0.f)*fcw_u;
      pv += __shfl_xor(pv, 1, 64);       // xor{1,2,4,8} stays within quad
      pv += __shfl_xor(pv, 2, 64);
      pv += __shfl_xor(pv, 4, 64);
      pv += __shfl_xor(pv, 8, 64);
      if(ln==0) parts[wv] = pv;          // quads 1-3 dup discarded
    }
    __syncthreads();
  }

  // ===== tail: ext(255) from last fc =====
  if(tid==0){
    float ext0 = ((parts[0]+parts[1])+(parts[2]+parts[3]))
               + ((parts[4]+parts[5])+(parts[6]+parts[7])) + fc2b0;
    extl[255]=f2bf(ext0);
  }
  __syncthreads();

  // ===== flush TOut / Ext_list from LDS =====
  if(tid<248){
    int i2 = tid + 8;
    out[bb*256+i2]      = bf2f(toutl[i2]);
    out[2*BT+bb*256+i2] = bf2f(extl[i2]);
  }
}

extern "C" void kernel_launch(void* const* d_in, const int* in_sizes, int n_in,
                              void* d_out, int out_size, void* d_ws, size_t ws_size,
                              hipStream_t stream)
{
  const float* in   = (const float*)d_in[0];
  const float* Wih  = (const float*)d_in[1];
  const float* Whh  = (const float*)d_in[2];
  const float* bih  = (const float*)d_in[3];
  const float* bhh  = (const float*)d_in[4];
  const float* fc1w = (const float*)d_in[5];
  const float* fc1b = (const float*)d_in[6];
  const float* fc2w = (const float*)d_in[7];
  const float* fc2b = (const float*)d_in[8];
  const float* i1w  = (const float*)d_in[9];
  const float* i1b  = (const float*)d_in[10];
  const float* i3w  = (const float*)d_in[11];
  const float* i3b  = (const float*)d_in[12];
  const float* scw  = (const float*)d_in[13];
  const float* zw   = (const float*)d_in[14];
  float* out = (float*)d_out;

  k_seq<<<dim3(512), dim3(512), 0, stream>>>(in, Wih, Whh, bih, bhh,
                                             fc1w, fc1b, fc2w, fc2b,
                                             i1w, i1b, i3w, i3b, scw, zw, out);
}

// Round 3
// 1444.859 us; speedup vs baseline: 1.2281x; 1.2281x over previous
//
#include <hip/hip_runtime.h>

#define BT   (512*256)
// hbuf (bytes): zeros @0..127, pad, h @192..319  (==64 mod 128: h line banks
// 16-31 for a0 / 0-15 for a1, opposite zero-lane banks -> max 2-way, free)
#define HB0b 192
#define HLENb 320
#define LOG2E 1.44269504088896f

using short8  = __attribute__((ext_vector_type(8))) short;
using floatx4 = __attribute__((ext_vector_type(4))) float;
using int4v   = __attribute__((ext_vector_type(4))) int;
using ushort4v= __attribute__((ext_vector_type(4))) unsigned short;

__device__ inline unsigned short f2bf(float f){
  unsigned int u = __float_as_uint(f);
  u += 0x7FFFu + ((u >> 16) & 1u);          // RNE
  return (unsigned short)(u >> 16);
}
__device__ inline float bf2f(unsigned short u){
  return __uint_as_float(((unsigned int)u) << 16);
}
__device__ inline float rcpf(float x){ return __builtin_amdgcn_rcpf(x); }
__device__ inline float ex2(float x){ return __builtin_amdgcn_exp2f(x); }

// 512 blocks x 512 threads, ONE batch per block, TARGET: 2 blocks/CU.
// Round-2 failed co-residency: arch(92)+acc VGPRs exceeded 128 total (the
// 4-waves/SIMD threshold on the unified gfx950 file) because launch_bounds
// (512,2) gave the allocator a 256-reg budget. This round: launch_bounds
// (512,4) = HARD 128-total cap + register diet so it fits without in-loop
// spills: x-gates packed to bf16 pairs via v_cvt_pk_bf16_f32 BEFORE the
// bpermute (xvp 16 regs instead of 32, 16 bpermutes instead of 32), and the
// per-gate K-chunk MFMAs made independent (z0,z1 + scalar add) instead of
// chained. Everything else identical to the 969us round-1 structure, minus
// the second batch.
__global__ __launch_bounds__(512,4) void k_seq(
    const float* __restrict__ in,
    const float* __restrict__ Wih,  const float* __restrict__ Whh,
    const float* __restrict__ bih,  const float* __restrict__ bhh,
    const float* __restrict__ fc1w, const float* __restrict__ fc1b,
    const float* __restrict__ fc2w, const float* __restrict__ fc2b,
    const float* __restrict__ i1w,  const float* __restrict__ i1b,
    const float* __restrict__ i3w,  const float* __restrict__ i3b,
    const float* __restrict__ scw,  const float* __restrict__ zonew,
    float* __restrict__ out)
{
  __shared__ __align__(16) signed char hbuf[2][HLENb];     // i8 h + zero region
  __shared__ __align__(16) float scratch[640];             // int-module weights
  __shared__ __align__(8)  unsigned short toutl[256];      // bf16 TOut history
  __shared__ __align__(8)  unsigned short extl[256];       // bf16 Ext results
  __shared__ __align__(16) unsigned short exl[1024];       // bf16 Ext_X cols [t][4]
  __shared__ float t0l[256];                               // T0 f32
  __shared__ float hvitl[256];                             // HVAC + int_all f32
  __shared__ __align__(16) float parts[8];                 // fc2 wave partials

  const int tid = threadIdx.x;
  const int wv  = tid >> 6;             // 0..7
  const int ln  = tid & 63;
  const int l15 = ln & 15;
  const int quad= ln >> 4;
  const int bb  = blockIdx.x;           // == batch index

  // ---- init: stage per-block tables ----
  if(tid<256){
    const float* row = in + bb*1792 + tid*7;
    t0l[tid] = row[0];
    exl[tid*4+0]=f2bf(row[1]); exl[tid*4+1]=f2bf(row[2]);
    exl[tid*4+2]=f2bf(row[3]); exl[tid*4+3]=f2bf(row[4]);
  }
  for(int p=tid; p<2*HLENb; p+=512) ((signed char*)hbuf)[p]=0;
  if(tid<8) toutl[tid] = f2bf(in[bb*1792+tid*7]);
  float* lw4 = scratch;
  float* l3  = scratch + 512;
  if(tid>=256 && tid<384){
    int j=tid-256;
    lw4[j*4+0]=i1w[j*3+0]; lw4[j*4+1]=i1w[j*3+1];
    lw4[j*4+2]=i1w[j*3+2]; lw4[j*4+3]=i1b[j];
    l3[j]=i3w[j];
  }
  __syncthreads();
  if(tid<128) hbuf[0][HB0b+tid] = 127;   // h=1.0 -> q=127

  // ---- fused int module (one t per thread, tid<256) ----
  if(tid<256){
    const float b30=i3b[0], sc0=scw[0];
    int t=tid;
    const float* row = in + bb*1792 + t*7;
    float x0=row[3],x1=row[4],x2=row[5], acc=0.f;
    #pragma unroll 8
    for(int j=0;j<128;j++){
      float r=fmaxf(lw4[j*4]*x0+lw4[j*4+1]*x1+lw4[j*4+2]*x2+lw4[j*4+3],0.f);
      acc += r*l3[j];
    }
    float v = rcpf(1.f+__expf(-(acc+b30)))*sc0;
    float itv = (t<8)?0.f:v;
    hvitl[t] = row[6] + itv;
    out[3*BT+bb*256+t]=itv;              // Int_list
    out[BT+bb*256+t]=row[6];             // HVAC_list
    if(t<8){ out[bb*256+t]=row[0]; out[2*BT+bb*256+t]=0.f; }
  }

  // ---- i8 weight quantization (per-row scale) into VGPRs ----
  int4v wq[4][2];        // [gate][K-chunk], rows n = 128g + 16wv + l15
  float dq[4];
  short8 xfr[4];         // W_ih bf16 (pre-scaled by log2e), K=32 pad (5 valid)
  float  bsum[4];
  #pragma unroll
  for(int g=0;g<4;g++){
    int n = 128*g + 16*wv + l15;
    bsum[g] = (bih[n]+bhh[n])*LOG2E;
    const float* wr = Whh + n*128;
    float mx = 1e-20f;
    for(int j=0;j<128;j++) mx = fmaxf(mx, fabsf(wr[j]));
    float qs = 127.f/mx;
    dq[g] = mx * (LOG2E/16129.f);        // log2e/127^2
    #pragma unroll
    for(int c=0;c<2;c++){
      int4v v4;
      #pragma unroll
      for(int d=0;d<4;d++){
        int pk=0;
        #pragma unroll
        for(int bq=0;bq<4;bq++){
          int kk = c*64 + quad*16 + d*4 + bq;
          int q = __float2int_rn(wr[kk]*qs);
          pk |= (q & 255) << (8*bq);
        }
        v4[d]=pk;
      }
      wq[g][c]=v4;
    }
    short8 f;
    #pragma unroll
    for(int j=0;j<8;j++){ int kk=quad*8+j; f[j]=(short)f2bf(kk<5?Wih[n*5+kk]*LOG2E:0.f); }
    xfr[g]=f;
  }
  int4v fq[2]; float dqf;                // fc1 i8 (NOT log2e-scaled), row n2 = 16wv + l15
  {
    int n2 = 16*wv + l15;
    const float* fr = fc1w + n2*128;
    float mx = 1e-20f;
    for(int j=0;j<128;j++) mx = fmaxf(mx, fabsf(fr[j]));
    float qs = 127.f/mx;
    dqf = mx * (1.f/16129.f);
    #pragma unroll
    for(int c=0;c<2;c++){
      int4v v4;
      #pragma unroll
      for(int d=0;d<4;d++){
        int pk=0;
        #pragma unroll
        for(int bq=0;bq<4;bq++){
          int kk = c*64 + quad*16 + d*4 + bq;
          int q = __float2int_rn(fr[kk]*qs);
          pk |= (q & 255) << (8*bq);
        }
        v4[d]=pk;
      }
      fq[c]=v4;
    }
  }

  // ---- per-lane persistent scalars ----
  const int  u     = 16*wv + l15;           // this lane's unit
  const int  arow  = ((l15&3)==0) ? HB0b : 0;   // rows 0,4,8,12 = batch; else zero
  const int  aoff  = arow + quad*16;
  const int  hwoff = HB0b + u;
  const int  bpa0  = l15<<2;                // bpermute byte addr, k<4 (rows 0-3)
  const int  bpa1  = bpa0 + 64;             // k>=4 (rows 4-7, lanes 16-31)
  const float fb    = fc1b[u];
  const float fcw_u = fc2w[u];
  const float fc2b0 = fc2b[0];
  const float zwv   = zonew[0];
  const floatx4 ZV  = {0.f,0.f,0.f,0.f};
  const int4v   ZI  = {0,0,0,0};
  const short8  Z8  = 0;
  float E0 = in[bb*1792 + 56];              // E in EVERY lane's registers
  float c0 = 1.f;
  __syncthreads();

  #pragma unroll 1
  for(int i=8;i<256;i++){
    // ===== phase A: deferred E-update (i-1), TOut, embed, x-MFMA+pack+bpermute =====
    if(i>8){
      floatx4 pa=*(const floatx4*)&parts[0];
      floatx4 pb=*(const floatx4*)&parts[4];
      float ext0=((pa[0]+pa[1])+(pa[2]+pa[3]))+((pb[0]+pb[1])+(pb[2]+pb[3]))+fc2b0;
      int ip = i-1;
      float tot0 = ext0 + hvitl[ip];
      if(ip<128){
        float ratio=(float)ip*0.0078125f;
        E0 = ratio*t0l[ip] + (1.f-ratio)*E0 + tot0*zwv;
      } else {
        E0 += tot0*zwv;
      }
      if(tid==0) extl[ip]=f2bf(ext0);
    }
    if(tid==0) toutl[i]=f2bf(E0);            // TOut[:,i]=E
    int xvp[8][2];                           // packed bf16 x-gate pairs: [k][{i|f, g|o}]
    {
      short8 ea = Z8;
      if(ln<8){                              // rows 0-7 = window slots
        int p=i-7+ln;
        float tos = (p==i) ? E0 : bf2f(toutl[p]);
        float tmix;
        if(i<128){
          float ratio=(float)i*0.0078125f;
          tmix = t0l[p]*ratio + tos*(1.f-ratio);
        } else tmix = tos;
        ea[0]=(short)f2bf(tmix);
        ushort4v e4 = *(const ushort4v*)&exl[p*4];
        ea[1]=(short)e4[0]; ea[2]=(short)e4[1];
        ea[3]=(short)e4[2]; ea[4]=(short)e4[3];
      }
      #pragma unroll
      for(int gp=0; gp<2; gp++){             // gate pairs (i,f) and (g,o)
        floatx4 zl=__builtin_amdgcn_mfma_f32_16x16x32_bf16(ea, xfr[2*gp],   ZV,0,0,0);
        floatx4 zh=__builtin_amdgcn_mfma_f32_16x16x32_bf16(ea, xfr[2*gp+1], ZV,0,0,0);
        #pragma unroll
        for(int r=0;r<4;r++){
          float lo = zl[r]+bsum[2*gp];
          float hi = zh[r]+bsum[2*gp+1];
          int pk;
          asm("v_cvt_pk_bf16_f32 %0, %1, %2" : "=v"(pk) : "v"(lo), "v"(hi));
          xvp[r][gp]   = __builtin_amdgcn_ds_bpermute(bpa0, pk);  // row r   (k=r)
          xvp[r+4][gp] = __builtin_amdgcn_ds_bpermute(bpa1, pk);  // row r+4 (k=r+4)
        }
      }
    }
    // NO barrier here: hbuf/parts already fenced by prev iter's barriers.

    // ===== 8 inner LSTM steps: 8 i8 MFMAs/wave, single nonlin chain =====
    #pragma unroll
    for(int k=0;k<8;k++){
      const signed char* hb = &hbuf[k&1][0];
      int4v a0 = *(const int4v*)(hb + aoff);        // K 0..63
      int4v a1 = *(const int4v*)(hb + aoff + 64);   // K 64..127
      int accs[4];
      #pragma unroll
      for(int g=0;g<4;g++){
        int4v za = __builtin_amdgcn_mfma_i32_16x16x64_i8(a0, wq[g][0], ZI,0,0,0);
        int4v zb = __builtin_amdgcn_mfma_i32_16x16x64_i8(a1, wq[g][1], ZI,0,0,0);
        accs[g] = za[0]+zb[0];                      // independent MFMAs, 1 add
      }
      int p0=xvp[k][0], p1=xvp[k][1];
      float xi = __uint_as_float(((unsigned)p0)<<16);
      float xf = __uint_as_float((unsigned)p0 & 0xffff0000u);
      float xgg= __uint_as_float(((unsigned)p1)<<16);
      float xo = __uint_as_float((unsigned)p1 & 0xffff0000u);
      float gi=fmaf((float)accs[0],dq[0],xi);       // all in log2e domain
      float gf=fmaf((float)accs[1],dq[1],xf);
      float gg=fmaf((float)accs[2],dq[2],xgg);
      float go=fmaf((float)accs[3],dq[3],xo);
      float ef =ex2(-gf);                           // bare v_exp
      float egi=ex2(-gi);
      float egg=ex2(-2.f*gg);
      float sf = rcpf(1.f+ef);
      float itn=(1.f-egg)*rcpf((1.f+egi)*(1.f+egg));
      c0 = sf*c0 + itn;
      float ego=ex2(-go);
      float ec =ex2(-2.8853900818f*c0);             // c unscaled: x2log2e
      float hv2=(1.f-ec)*rcpf((1.f+ego)*(1.f+ec));
      int q = __float2int_rn(hv2*127.f);            // |h|<1 -> |q|<=127
      hbuf[(k+1)&1][hwoff] = (signed char)q;        // quads 1-3 dup same value
      __syncthreads();
    }

    // ===== fc1 (i8) + within-quad fc2 reduce =====
    {
      const signed char* hb = &hbuf[0][0];
      int4v a0 = *(const int4v*)(hb + aoff);
      int4v a1 = *(const int4v*)(hb + aoff + 64);
      int4v za = __builtin_amdgcn_mfma_i32_16x16x64_i8(a0, fq[0], ZI,0,0,0);
      int4v zb = __builtin_amdgcn_mfma_i32_16x16x64_i8(a1, fq[1], ZI,0,0,0);
      float fv = (float)(za[0]+zb[0])*dqf + fb;
      float pv = fmaxf(fv,0.f)*fcw_u;
      pv += __shfl_xor(pv, 1, 64);       // xor{1,2,4,8} stays within quad
      pv += __shfl_xor(pv, 2, 64);
      pv += __shfl_xor(pv, 4, 64);
      pv += __shfl_xor(pv, 8, 64);
      if(ln==0) parts[wv] = pv;          // quads 1-3 dup discarded
    }
    __syncthreads();
  }

  // ===== tail: ext(255) from last fc =====
  if(tid==0){
    float ext0 = ((parts[0]+parts[1])+(parts[2]+parts[3]))
               + ((parts[4]+parts[5])+(parts[6]+parts[7])) + fc2b0;
    extl[255]=f2bf(ext0);
  }
  __syncthreads();

  // ===== flush TOut / Ext_list from LDS =====
  if(tid<248){
    int i2 = tid + 8;
    out[bb*256+i2]      = bf2f(toutl[i2]);
    out[2*BT+bb*256+i2] = bf2f(extl[i2]);
  }
}

extern "C" void kernel_launch(void* const* d_in, const int* in_sizes, int n_in,
                              void* d_out, int out_size, void* d_ws, size_t ws_size,
                              hipStream_t stream)
{
  const float* in   = (const float*)d_in[0];
  const float* Wih  = (const float*)d_in[1];
  const float* Whh  = (const float*)d_in[2];
  const float* bih  = (const float*)d_in[3];
  const float* bhh  = (const float*)d_in[4];
  const float* fc1w = (const float*)d_in[5];
  const float* fc1b = (const float*)d_in[6];
  const float* fc2w = (const float*)d_in[7];
  const float* fc2b = (const float*)d_in[8];
  const float* i1w  = (const float*)d_in[9];
  const float* i1b  = (const float*)d_in[10];
  const float* i3w  = (const float*)d_in[11];
  const float* i3b  = (const float*)d_in[12];
  const float* scw  = (const float*)d_in[13];
  const float* zw   = (const float*)d_in[14];
  float* out = (float*)d_out;

  k_seq<<<dim3(512), dim3(512), 0, stream>>>(in, Wih, Whh, bih, bhh,
                                             fc1w, fc1b, fc2w, fc2b,
                                             i1w, i1b, i3w, i3b, scw, zw, out);
}